// Round 3
// baseline (144.424 us; speedup 1.0000x reference)
//
#include <hip/hip_runtime.h>

// N=512, S=64, C=1024, B=10, PAD=0, NEG=-1e9
#define NN 512
#define SS 64
#define CC 1024
#define BB 10
#define SH 32      // s-rows per block (half a row; stats recomputed 2x per n)
#define CH 8       // s-rows per epilogue chunk

// Single fused kernel: one dispatch, no workspace, no inter-kernel gap.
// Block = (n, half-of-s), 256 threads. Stats prologue (~few us, amortized
// across 4 blocks/CU), then the proven LDS-free chunked streaming epilogue:
// ban masks from block-uniform scalar loads + 3 VALU/id, 8 float4 stores
// per thread per chunk, plain (cached) stores so L3 can absorb.
__global__ __launch_bounds__(256) void spop_fused(
    const int* __restrict__ ban_ids,    // [N,S,B]
    const int* __restrict__ item_ids,   // [N,S]
    float* __restrict__ out_pi,         // [N,S,C]
    float* __restrict__ out_v)          // [N,S]
{
    const int tid  = threadIdx.x;
    const int lane = tid & 63;
    const int wid  = tid >> 6;
    const int n    = blockIdx.x >> 1;
    const int s0   = (blockIdx.x & 1) * SH;
    const int b0   = n * SS + s0;

    __shared__ __align__(16) float cnt[CC];   // 4 KB histogram
    __shared__ float lse_s[SH];
    __shared__ float red_m[4], red_s[4];

    // ---- zero histogram ----
    *reinterpret_cast<float4*>(&cnt[tid * 4]) = make_float4(0.f, 0.f, 0.f, 0.f);
    __syncthreads();

    // ---- histogram (wave 0), dropping the LAST non-pad item ----
    if (tid < 64) {
        int id = item_ids[n * SS + tid];
        bool nonpad = (id != 0);
        unsigned long long m = __ballot(nonpad);
        int last = 63 - __clzll(m | 1ull);
        if (nonpad && tid != last) atomicAdd(&cnt[id], 1.0f);
    }
    __syncthreads();

    // ---- each thread owns classes 4*tid..4*tid+3 ----
    const float4 c4 = *reinterpret_cast<const float4*>(&cnt[tid * 4]);

    // block max
    float mx = fmaxf(fmaxf(c4.x, c4.y), fmaxf(c4.z, c4.w));
#pragma unroll
    for (int off = 32; off >= 1; off >>= 1)
        mx = fmaxf(mx, __shfl_xor(mx, off));
    if (lane == 0) red_m[wid] = mx;
    __syncthreads();
    mx = fmaxf(fmaxf(red_m[0], red_m[1]), fmaxf(red_m[2], red_m[3]));

    // block sum of exp
    float se = __expf(c4.x - mx) + __expf(c4.y - mx) +
               __expf(c4.z - mx) + __expf(c4.w - mx);
#pragma unroll
    for (int off = 32; off >= 1; off >>= 1)
        se += __shfl_xor(se, off);
    if (lane == 0) red_s[wid] = se;
    __syncthreads();
    const float sumall = red_s[0] + red_s[1] + red_s[2] + red_s[3];

    // ---- per-s lse with ban dedup (threads 0..31, one s each) ----
    if (tid < SH) {
        int ban[BB];
#pragma unroll
        for (int j = 0; j < BB; ++j)
            ban[j] = ban_ids[(size_t)(b0 + tid) * BB + j];
        float bsum = 0.f;
#pragma unroll
        for (int j = 0; j < BB; ++j) {
            bool dup = false;
#pragma unroll
            for (int k = 0; k < BB; ++k)
                if (k < j) dup |= (ban[k] == ban[j]);
            if (!dup) bsum += __expf(cnt[ban[j]] - mx);
        }
        float valid = fmaxf(sumall - bsum, 1e-30f);
        lse_s[tid] = mx + __logf(valid);
        out_v[b0 + tid] = 0.0f;
    }
    __syncthreads();

    // ---- chunked streaming epilogue (LDS-free mask via uniform compares) ----
    float4* obase = reinterpret_cast<float4*>(&out_pi[(size_t)b0 * CC]) + tid;
#pragma unroll
    for (int c0 = 0; c0 < SH; c0 += CH) {
        float    lse_r[CH];
        unsigned m4_r[CH];
#pragma unroll
        for (int s = 0; s < CH; ++s) {
            lse_r[s] = lse_s[c0 + s];                     // LDS broadcast
            const int* bp = &ban_ids[(size_t)(b0 + c0 + s) * BB];
            unsigned m4 = 0u;
#pragma unroll
            for (int j = 0; j < BB; ++j) {
                const int c = bp[j];                      // block-uniform -> s_load
                if ((c >> 2) == tid) m4 |= 1u << (c & 3);
            }
            m4_r[s] = m4;
        }
#pragma unroll
        for (int s = 0; s < CH; ++s) {
            float4 v = c4;
            if (m4_r[s] & 1u) v.x -= 1e9f;
            if (m4_r[s] & 2u) v.y -= 1e9f;
            if (m4_r[s] & 4u) v.z -= 1e9f;
            if (m4_r[s] & 8u) v.w -= 1e9f;
            const float l = lse_r[s];
            obase[(size_t)(c0 + s) * (CC / 4)] =
                make_float4(v.x - l, v.y - l, v.z - l, v.w - l);
        }
    }
}

extern "C" void kernel_launch(void* const* d_in, const int* in_sizes, int n_in,
                              void* d_out, int out_size, void* d_ws, size_t ws_size,
                              hipStream_t stream) {
    const int* ban_ids  = (const int*)d_in[1];
    const int* item_ids = (const int*)d_in[2];
    float* out_pi = (float*)d_out;                      // [N,S,C]
    float* out_v  = out_pi + (size_t)NN * SS * CC;      // [N,S]

    spop_fused<<<dim3(NN * (SS / SH)), dim3(256), 0, stream>>>(
        ban_ids, item_ids, out_pi, out_v);
}